// Round 4
// baseline (60447.522 us; speedup 1.0000x reference)
//
#include <hip/hip_runtime.h>

#define T_STEPS 32768
#define OUT_BASE 9830400  // 32768*300

typedef _Float16 h2 __attribute__((ext_vector_type(2)));

__device__ __forceinline__ float fdot2(h2 a, h2 b, float c) {
#if __has_builtin(__builtin_amdgcn_fdot2)
    return __builtin_amdgcn_fdot2(a, b, c, false);
#else
    return c + (float)a.x * (float)b.x + (float)a.y * (float)b.y;
#endif
}

#define BC2(f_) __builtin_bit_cast(h2, f_)

__device__ __forceinline__ float sigf(float x) { return 1.f / (1.f + __expf(-x)); }

__device__ __forceinline__ float tanh_f(float x) {
    float a = fabsf(x);
    float e = __expf(-2.f * a);
    float t = (1.f - e) / (1.f + e);
    return x < 0.f ? -t : t;
}

// LDS-only barrier: no vmcnt(0) drain (x prefetch / h1s stores have no
// cross-thread dependency inside this kernel).
__device__ __forceinline__ void bar_lds() {
    asm volatile("s_waitcnt lgkmcnt(0)\n\ts_barrier" ::: "memory");
}

// ---------------- A0: Wc = W_ih_l0 @ W_inp  [400x300]; bc = W_ih_l0@b_inp + b_ih0 + b_hh0 ----------------
__global__ void k_precomp(const float* __restrict__ W_inp, const float* __restrict__ b_inp,
                          const float* __restrict__ W_ih0, const float* __restrict__ b_ih0,
                          const float* __restrict__ b_hh0,
                          float* __restrict__ Wc, float* __restrict__ bc) {
    int idx = blockIdx.x * 256 + threadIdx.x;
    if (idx < 120000) {
        int r = idx / 300, d = idx % 300;
        float acc = 0.f;
        for (int h = 0; h < 100; h++) acc += W_ih0[r * 100 + h] * W_inp[h * 300 + d];
        Wc[idx] = acc;
    } else if (idx < 120400) {
        int r = idx - 120000;
        float acc = b_ih0[r] + b_hh0[r];
        for (int h = 0; h < 100; h++) acc += W_ih0[r * 100 + h] * b_inp[h];
        bc[r] = acc;
    }
}

// ---------------- A1: x0p[t][r] = inputs[t] . Wc[r] + bc[r], stored f16 ----------------
__global__ __launch_bounds__(512) void k_xproj(const float* __restrict__ inp,
                                               const float* __restrict__ Wc,
                                               const float* __restrict__ bc,
                                               _Float16* __restrict__ x0p) {
    __shared__ float xs[32 * 300];
    int t0 = blockIdx.x * 32;
    for (int idx = threadIdx.x; idx < 9600; idx += 512) xs[idx] = inp[(size_t)t0 * 300 + idx];
    __syncthreads();
    int j = threadIdx.x;
    if (j < 400) {
        float acc[32];
#pragma unroll
        for (int i = 0; i < 32; i++) acc[i] = 0.f;
        const float4* w4 = (const float4*)(Wc + j * 300);
        const float4* x4 = (const float4*)xs;
        for (int d4 = 0; d4 < 75; d4++) {
            float4 w = w4[d4];
#pragma unroll
            for (int ti = 0; ti < 32; ti++) {
                float4 x = x4[ti * 75 + d4];
                acc[ti] += w.x * x.x + w.y * x.y + w.z * x.z + w.w * x.w;
            }
        }
        float bb = bc[j];
#pragma unroll
        for (int ti = 0; ti < 32; ti++)
            x0p[(size_t)(t0 + ti) * 400 + j] = (_Float16)(acc[ti] + bb);
    }
}

// ---------------- Scan: 1024 threads, each gate-row dot split across two threads ----------------
// Group A (threads 0-399):   wx = W_hh0[row][0:50]   (25 pairs + 3 zero-pad)
//                            wy = W_ih1[row][0:100]  (50 pairs + 2 zero-pad), owns x and b1
// Group B (threads 512-911): wx = W_hh0[row][50:100] (25 pairs + 3 zero-pad)
//                            wy = W_hh1[row][0:100]  (50 pairs + 2 zero-pad)
// 80 packed-f16 weight VGPRs per thread -> fits the 128-VGPR budget at 16 waves/CU
// (round-3's 150-reg version spilled to scratch: 13 GB FETCH + 12.8 GB WRITE per dispatch).
// LDS h-state mirrors, zero-padded so every read is an aligned float4:
//   hA[52] = h0 pairs 0-49, [50,51]=0
//   hB[80] = h0 pairs 25-49, [25:28]=0, h1 pairs 0-49 at [28:78], [78,79]=0
// Pipelined: tick t computes gates0(t) and gates1(t-1). 2 LDS-only barriers/tick.

#define TICK(T_, XR_, PX_) do {                                                              \
    if (gA) {                                                                                \
        float xc_ = XR_;                                                                     \
        XR_ = (float)*PX_; PX_ += 800;                                                       \
        const float4* a4_ = (const float4*)hA;                                               \
        float acc0_ = xc_, acc1_ = b1c;                                                      \
        _Pragma("unroll")                                                                    \
        for (int c_ = 0; c_ < 7; c_++) {                                                     \
            float4 v_ = a4_[c_];                                                             \
            acc0_ = fdot2(wx[4 * c_ + 0], BC2(v_.x), acc0_);                                 \
            acc1_ = fdot2(wy[4 * c_ + 0], BC2(v_.x), acc1_);                                 \
            acc0_ = fdot2(wx[4 * c_ + 1], BC2(v_.y), acc0_);                                 \
            acc1_ = fdot2(wy[4 * c_ + 1], BC2(v_.y), acc1_);                                 \
            acc0_ = fdot2(wx[4 * c_ + 2], BC2(v_.z), acc0_);                                 \
            acc1_ = fdot2(wy[4 * c_ + 2], BC2(v_.z), acc1_);                                 \
            acc0_ = fdot2(wx[4 * c_ + 3], BC2(v_.w), acc0_);                                 \
            acc1_ = fdot2(wy[4 * c_ + 3], BC2(v_.w), acc1_);                                 \
        }                                                                                    \
        _Pragma("unroll")                                                                    \
        for (int c_ = 7; c_ < 13; c_++) {                                                    \
            float4 v_ = a4_[c_];                                                             \
            acc1_ = fdot2(wy[4 * c_ + 0], BC2(v_.x), acc1_);                                 \
            acc1_ = fdot2(wy[4 * c_ + 1], BC2(v_.y), acc1_);                                 \
            acc1_ = fdot2(wy[4 * c_ + 2], BC2(v_.z), acc1_);                                 \
            acc1_ = fdot2(wy[4 * c_ + 3], BC2(v_.w), acc1_);                                 \
        }                                                                                    \
        pa0[j] = acc0_; pa1[j] = acc1_;                                                      \
    } else if (gB) {                                                                         \
        const float4* b4_ = (const float4*)hB;                                               \
        float acc0_ = 0.f, acc1_ = 0.f;                                                      \
        _Pragma("unroll")                                                                    \
        for (int c_ = 0; c_ < 7; c_++) {                                                     \
            float4 v_ = b4_[c_];                                                             \
            acc0_ = fdot2(wx[4 * c_ + 0], BC2(v_.x), acc0_);                                 \
            acc0_ = fdot2(wx[4 * c_ + 1], BC2(v_.y), acc0_);                                 \
            acc0_ = fdot2(wx[4 * c_ + 2], BC2(v_.z), acc0_);                                 \
            acc0_ = fdot2(wx[4 * c_ + 3], BC2(v_.w), acc0_);                                 \
        }                                                                                    \
        _Pragma("unroll")                                                                    \
        for (int c_ = 7; c_ < 20; c_++) {                                                    \
            float4 v_ = b4_[c_];                                                             \
            acc1_ = fdot2(wy[4 * (c_ - 7) + 0], BC2(v_.x), acc1_);                           \
            acc1_ = fdot2(wy[4 * (c_ - 7) + 1], BC2(v_.y), acc1_);                           \
            acc1_ = fdot2(wy[4 * (c_ - 7) + 2], BC2(v_.z), acc1_);                           \
            acc1_ = fdot2(wy[4 * (c_ - 7) + 3], BC2(v_.w), acc1_);                           \
        }                                                                                    \
        pb0[ib] = acc0_; pb1[ib] = acc1_;                                                    \
    }                                                                                        \
    bar_lds();                                                                               \
    if (j < 100) {  /* layer-0 update, step T_ */                                            \
        float gi_ = pa0[j] + pb0[j];                                                         \
        float gf_ = pa0[j + 100] + pb0[j + 100];                                             \
        float gg_ = pa0[j + 200] + pb0[j + 200];                                             \
        float go_ = pa0[j + 300] + pb0[j + 300];                                             \
        c0 = sigf(gf_) * c0 + sigf(gi_) * tanh_f(gg_);                                       \
        h0v = sigf(go_) * tanh_f(c0);                                                        \
        float hp_ = __shfl_xor(h0v, 1);                                                      \
        if (!(j & 1)) {                                                                      \
            h2 q_; q_.x = (_Float16)h0v; q_.y = (_Float16)hp_;                               \
            unsigned int u_ = __builtin_bit_cast(unsigned int, q_);                          \
            int p_ = j >> 1;                                                                 \
            hA[p_] = u_;                                                                     \
            if (p_ >= 25) hB[p_ - 25] = u_;                                                  \
        }                                                                                    \
        if ((T_) == T_STEPS - 1) { outTail[j] = h0v; outTail[200 + j] = c0; }                \
    } else if (ib >= 0 && ib < 100) {  /* layer-1 update, step T_-1 */                       \
        if ((T_) >= 1) {                                                                     \
            float gi_ = pa1[ib] + pb1[ib];                                                   \
            float gf_ = pa1[ib + 100] + pb1[ib + 100];                                       \
            float gg_ = pa1[ib + 200] + pb1[ib + 200];                                       \
            float go_ = pa1[ib + 300] + pb1[ib + 300];                                       \
            c1 = sigf(gf_) * c1 + sigf(gi_) * tanh_f(gg_);                                   \
            h1v = sigf(go_) * tanh_f(c1);                                                    \
            h1s[(size_t)((T_) - 1) * 100 + ib] = h1v;                                        \
            float hp_ = __shfl_xor(h1v, 1);                                                  \
            if (!(ib & 1)) {                                                                 \
                h2 q_; q_.x = (_Float16)h1v; q_.y = (_Float16)hp_;                           \
                hB[28 + (ib >> 1)] = __builtin_bit_cast(unsigned int, q_);                   \
            }                                                                                \
        }                                                                                    \
    }                                                                                        \
    bar_lds();                                                                               \
} while (0)

__global__ __launch_bounds__(1024) void k_scan(const _Float16* __restrict__ x0p,
                                               const float* __restrict__ Whh0,
                                               const float* __restrict__ Wih1,
                                               const float* __restrict__ Whh1,
                                               const float* __restrict__ bih1,
                                               const float* __restrict__ bhh1,
                                               float* __restrict__ h1s,
                                               float* __restrict__ outTail) {
    __shared__ __align__(16) unsigned int hA[52];
    __shared__ __align__(16) unsigned int hB[80];
    __shared__ float pa0[400], pb0[400], pa1[400], pb1[400];
    const int j = threadIdx.x;
    const int ib = j - 512;
    const bool gA = (j < 400);
    const bool gB = (ib >= 0 && ib < 400);

    h2 wx[28];  // half of W_hh0 row (+3 zero-pad)
    h2 wy[52];  // full W_ih1 row (A) or W_hh1 row (B) (+2 zero-pad)
    h2 zz; zz.x = (_Float16)0.f; zz.y = (_Float16)0.f;
    float b1c = 0.f, xa = 0.f, xb = 0.f;
    const _Float16* pxa = x0p + 800 + j;
    const _Float16* pxb = x0p + 1200 + j;

    if (gA) {
        const float2* p0 = (const float2*)(Whh0 + j * 100);
#pragma unroll
        for (int k = 0; k < 25; k++) { float2 v = p0[k]; h2 q; q.x = (_Float16)v.x; q.y = (_Float16)v.y; wx[k] = q; }
        wx[25] = zz; wx[26] = zz; wx[27] = zz;
        const float2* p1 = (const float2*)(Wih1 + j * 100);
#pragma unroll
        for (int k = 0; k < 50; k++) { float2 v = p1[k]; h2 q; q.x = (_Float16)v.x; q.y = (_Float16)v.y; wy[k] = q; }
        wy[50] = zz; wy[51] = zz;
        b1c = bih1[j] + bhh1[j];
        xa = (float)x0p[j];        // x(0)
        xb = (float)x0p[400 + j];  // x(1)
    } else if (gB) {
        const float2* p0 = (const float2*)(Whh0 + ib * 100 + 50);
#pragma unroll
        for (int k = 0; k < 25; k++) { float2 v = p0[k]; h2 q; q.x = (_Float16)v.x; q.y = (_Float16)v.y; wx[k] = q; }
        wx[25] = zz; wx[26] = zz; wx[27] = zz;
        const float2* p1 = (const float2*)(Whh1 + ib * 100);
#pragma unroll
        for (int k = 0; k < 50; k++) { float2 v = p1[k]; h2 q; q.x = (_Float16)v.x; q.y = (_Float16)v.y; wy[k] = q; }
        wy[50] = zz; wy[51] = zz;
    }
    if (j < 52) hA[j] = 0u;
    if (j < 80) hB[j] = 0u;
    float c0 = 0.f, c1 = 0.f, h0v = 0.f, h1v = 0.f;
    __syncthreads();

    for (int t = 0; t < T_STEPS; t += 2) {
        TICK(t, xa, pxa);      // distance-2 prefetch
        TICK(t + 1, xb, pxb);
    }

    // Drain: gates1 for step T-1, then final layer-1 update.
    if (gA) {
        const float4* a4 = (const float4*)hA;
        float acc1 = b1c;
#pragma unroll
        for (int c = 0; c < 13; c++) {
            float4 v = a4[c];
            acc1 = fdot2(wy[4 * c + 0], BC2(v.x), acc1);
            acc1 = fdot2(wy[4 * c + 1], BC2(v.y), acc1);
            acc1 = fdot2(wy[4 * c + 2], BC2(v.z), acc1);
            acc1 = fdot2(wy[4 * c + 3], BC2(v.w), acc1);
        }
        pa1[j] = acc1;
    } else if (gB) {
        const float4* b4 = (const float4*)hB;
        float acc1 = 0.f;
#pragma unroll
        for (int c = 7; c < 20; c++) {
            float4 v = b4[c];
            acc1 = fdot2(wy[4 * (c - 7) + 0], BC2(v.x), acc1);
            acc1 = fdot2(wy[4 * (c - 7) + 1], BC2(v.y), acc1);
            acc1 = fdot2(wy[4 * (c - 7) + 2], BC2(v.z), acc1);
            acc1 = fdot2(wy[4 * (c - 7) + 3], BC2(v.w), acc1);
        }
        pb1[ib] = acc1;
    }
    bar_lds();
    if (ib >= 0 && ib < 100) {
        float gi = pa1[ib] + pb1[ib];
        float gf = pa1[ib + 100] + pb1[ib + 100];
        float gg = pa1[ib + 200] + pb1[ib + 200];
        float go = pa1[ib + 300] + pb1[ib + 300];
        c1 = sigf(gf) * c1 + sigf(gi) * tanh_f(gg);
        h1v = sigf(go) * tanh_f(c1);
        h1s[(size_t)(T_STEPS - 1) * 100 + ib] = h1v;
        outTail[100 + ib] = h1v;
        outTail[300 + ib] = c1;
    }
}

// ---------------- C: outputs[t][d] = h1s[t] . W_out[d] + b_out[d] ----------------
__global__ __launch_bounds__(320) void k_out(const float* __restrict__ h1s,
                                             const float* __restrict__ Wout,
                                             const float* __restrict__ bout,
                                             float* __restrict__ out) {
    __shared__ float hs[32 * 100];
    int t0 = blockIdx.x * 32;
    for (int idx = threadIdx.x; idx < 3200; idx += 320) hs[idx] = h1s[(size_t)t0 * 100 + idx];
    __syncthreads();
    int d = threadIdx.x;
    if (d < 300) {
        float acc[32];
#pragma unroll
        for (int i = 0; i < 32; i++) acc[i] = 0.f;
        const float4* w4 = (const float4*)(Wout + d * 100);
        const float4* h4 = (const float4*)hs;
        for (int j4 = 0; j4 < 25; j4++) {
            float4 w = w4[j4];
#pragma unroll
            for (int ti = 0; ti < 32; ti++) {
                float4 h = h4[ti * 25 + j4];
                acc[ti] += w.x * h.x + w.y * h.y + w.z * h.z + w.w * h.w;
            }
        }
        float bb = bout[d];
#pragma unroll
        for (int ti = 0; ti < 32; ti++) out[(size_t)(t0 + ti) * 300 + d] = acc[ti] + bb;
    }
}

extern "C" void kernel_launch(void* const* d_in, const int* in_sizes, int n_in,
                              void* d_out, int out_size, void* d_ws, size_t ws_size,
                              hipStream_t stream) {
    const float* inputs = (const float*)d_in[0];
    const float* W_inp  = (const float*)d_in[1];
    const float* b_inp  = (const float*)d_in[2];
    const float* W_ih0  = (const float*)d_in[3];
    const float* W_hh0  = (const float*)d_in[4];
    const float* b_ih0  = (const float*)d_in[5];
    const float* b_hh0  = (const float*)d_in[6];
    const float* W_ih1  = (const float*)d_in[7];
    const float* W_hh1  = (const float*)d_in[8];
    const float* b_ih1  = (const float*)d_in[9];
    const float* b_hh1  = (const float*)d_in[10];
    const float* W_out  = (const float*)d_in[11];
    const float* b_out  = (const float*)d_in[12];
    float* out = (float*)d_out;

    char* ws = (char*)d_ws;
    _Float16* x0p = (_Float16*)ws;                         // 32768*400*2 = 26,214,400 B
    float* h1s = (float*)(ws + 26214400);                  // 32768*100*4 = 13,107,200 B
    float* Wc  = (float*)(ws + 26214400 + 13107200);       // 400*300*4   =    480,000 B
    float* bc  = Wc + 120000;                              // 400*4 B

    k_precomp<<<471, 256, 0, stream>>>(W_inp, b_inp, W_ih0, b_ih0, b_hh0, Wc, bc);
    k_xproj<<<1024, 512, 0, stream>>>(inputs, Wc, bc, x0p);
    k_scan<<<1, 1024, 0, stream>>>(x0p, W_hh0, W_ih1, W_hh1, b_ih1, b_hh1, h1s, out + OUT_BASE);
    k_out<<<1024, 320, 0, stream>>>(h1s, W_out, b_out, out);
}

// Round 5
// 59019.824 us; speedup vs baseline: 1.0242x; 1.0242x over previous
//
#include <hip/hip_runtime.h>

#define T_STEPS 32768
#define OUT_BASE 9830400  // 32768*300

typedef _Float16 h2 __attribute__((ext_vector_type(2)));

__device__ __forceinline__ float fdot2(h2 a, h2 b, float c) {
#if __has_builtin(__builtin_amdgcn_fdot2)
    return __builtin_amdgcn_fdot2(a, b, c, false);
#else
    return c + (float)a.x * (float)b.x + (float)a.y * (float)b.y;
#endif
}

#define BC2(f_) __builtin_bit_cast(h2, f_)

__device__ __forceinline__ float packpair(float2 v) {
    h2 q; q.x = (_Float16)v.x; q.y = (_Float16)v.y;
    return __builtin_bit_cast(float, q);
}

__device__ __forceinline__ float sigf(float x) { return 1.f / (1.f + __expf(-x)); }

__device__ __forceinline__ float tanh_f(float x) {
    float a = fabsf(x);
    float e = __expf(-2.f * a);
    float t = (1.f - e) / (1.f + e);
    return x < 0.f ? -t : t;
}

// Explicit AGPR residence: the allocator has spilled weight arrays to scratch in
// every config tried (13 GB HBM round-trip/dispatch). "a"-class constraints force
// the unified-file AGPR half, which the arch-VGPR occupancy heuristic doesn't touch.
// AREAD is volatile so the 75 loop reads aren't hoisted (which would recreate the
// arch-pressure problem).
#define AWRITE(dst_, src_) asm("v_accvgpr_write_b32 %0, %1" : "=a"(dst_) : "v"(src_))
#define AREAD(dst_, src_)  asm volatile("v_accvgpr_read_b32 %0, %1" : "=v"(dst_) : "a"(src_))

// LDS-only barrier: no vmcnt(0) drain (x prefetch / h1s stores have no
// cross-thread dependency inside this kernel).
__device__ __forceinline__ void bar_lds() {
    asm volatile("s_waitcnt lgkmcnt(0)\n\ts_barrier" ::: "memory");
}

// ---------------- A0: Wc = W_ih_l0 @ W_inp  [400x300]; bc = W_ih_l0@b_inp + b_ih0 + b_hh0 ----------------
__global__ void k_precomp(const float* __restrict__ W_inp, const float* __restrict__ b_inp,
                          const float* __restrict__ W_ih0, const float* __restrict__ b_ih0,
                          const float* __restrict__ b_hh0,
                          float* __restrict__ Wc, float* __restrict__ bc) {
    int idx = blockIdx.x * 256 + threadIdx.x;
    if (idx < 120000) {
        int r = idx / 300, d = idx % 300;
        float acc = 0.f;
        for (int h = 0; h < 100; h++) acc += W_ih0[r * 100 + h] * W_inp[h * 300 + d];
        Wc[idx] = acc;
    } else if (idx < 120400) {
        int r = idx - 120000;
        float acc = b_ih0[r] + b_hh0[r];
        for (int h = 0; h < 100; h++) acc += W_ih0[r * 100 + h] * b_inp[h];
        bc[r] = acc;
    }
}

// ---------------- A1: x0p[t][r] = inputs[t] . Wc[r] + bc[r], stored f16 ----------------
__global__ __launch_bounds__(512) void k_xproj(const float* __restrict__ inp,
                                               const float* __restrict__ Wc,
                                               const float* __restrict__ bc,
                                               _Float16* __restrict__ x0p) {
    __shared__ float xs[32 * 300];
    int t0 = blockIdx.x * 32;
    for (int idx = threadIdx.x; idx < 9600; idx += 512) xs[idx] = inp[(size_t)t0 * 300 + idx];
    __syncthreads();
    int j = threadIdx.x;
    if (j < 400) {
        float acc[32];
#pragma unroll
        for (int i = 0; i < 32; i++) acc[i] = 0.f;
        const float4* w4 = (const float4*)(Wc + j * 300);
        const float4* x4 = (const float4*)xs;
        for (int d4 = 0; d4 < 75; d4++) {
            float4 w = w4[d4];
#pragma unroll
            for (int ti = 0; ti < 32; ti++) {
                float4 x = x4[ti * 75 + d4];
                acc[ti] += w.x * x.x + w.y * x.y + w.z * x.z + w.w * x.w;
            }
        }
        float bb = bc[j];
#pragma unroll
        for (int ti = 0; ti < 32; ti++)
            x0p[(size_t)(t0 + ti) * 400 + j] = (_Float16)(acc[ti] + bb);
    }
}

// ---------------- Scan: 512 threads, pipelined (layer1 lags 1 tick), AGPR-resident weights ----------------
// Thread j<400 per-tick: gates0(t)[j] = x(t)[j] + W_hh0[j]·h0(t-1)
//                        gates1(t-1)[j] = b1[j] + W_ih1[j]·h0(t-1) + W_hh1[j]·h1(t-2)
// hcat[0..49]=h0 pairs, [50..99]=h1 pairs (packed f16), read as 25 aligned float4.
// Arch VGPRs: wx[25] (W_hh0 pairs 0-24) + wy[50] (W_ih1) = 75 + ~25 working.
// AGPRs:      wxa[25] (W_hh0 pairs 25-49) + wza[50] (W_hh1) = 75.

#define TICK(T_, XR_, PX_) do {                                                              \
    if (j < 400) {                                                                           \
        float xc_ = XR_;                                                                     \
        XR_ = (float)*PX_; PX_ += 800;                                                       \
        const float4* h4_ = (const float4*)hcat;                                             \
        float acc0_ = xc_, acc1_ = b1c, t_;                                                  \
        _Pragma("unroll")                                                                    \
        for (int c_ = 0; c_ < 6; c_++) {  /* h0 pairs 0..23: arch wx + wy */                 \
            float4 v_ = h4_[c_];                                                             \
            acc0_ = fdot2(BC2(wx[4 * c_ + 0]), BC2(v_.x), acc0_);                            \
            acc1_ = fdot2(BC2(wy[4 * c_ + 0]), BC2(v_.x), acc1_);                            \
            acc0_ = fdot2(BC2(wx[4 * c_ + 1]), BC2(v_.y), acc0_);                            \
            acc1_ = fdot2(BC2(wy[4 * c_ + 1]), BC2(v_.y), acc1_);                            \
            acc0_ = fdot2(BC2(wx[4 * c_ + 2]), BC2(v_.z), acc0_);                            \
            acc1_ = fdot2(BC2(wy[4 * c_ + 2]), BC2(v_.z), acc1_);                            \
            acc0_ = fdot2(BC2(wx[4 * c_ + 3]), BC2(v_.w), acc0_);                            \
            acc1_ = fdot2(BC2(wy[4 * c_ + 3]), BC2(v_.w), acc1_);                            \
        }                                                                                    \
        {  /* c=6: h0 pairs 24..27 — wx[24] arch, wxa[0..2] AGPR */                          \
            float4 v_ = h4_[6];                                                              \
            acc0_ = fdot2(BC2(wx[24]), BC2(v_.x), acc0_);                                    \
            acc1_ = fdot2(BC2(wy[24]), BC2(v_.x), acc1_);                                    \
            AREAD(t_, wxa[0]); acc0_ = fdot2(BC2(t_), BC2(v_.y), acc0_);                     \
            acc1_ = fdot2(BC2(wy[25]), BC2(v_.y), acc1_);                                    \
            AREAD(t_, wxa[1]); acc0_ = fdot2(BC2(t_), BC2(v_.z), acc0_);                     \
            acc1_ = fdot2(BC2(wy[26]), BC2(v_.z), acc1_);                                    \
            AREAD(t_, wxa[2]); acc0_ = fdot2(BC2(t_), BC2(v_.w), acc0_);                     \
            acc1_ = fdot2(BC2(wy[27]), BC2(v_.w), acc1_);                                    \
        }                                                                                    \
        _Pragma("unroll")                                                                    \
        for (int c_ = 7; c_ < 12; c_++) {  /* h0 pairs 28..47: wxa AGPR + wy arch */         \
            float4 v_ = h4_[c_];                                                             \
            AREAD(t_, wxa[4 * c_ - 25]); acc0_ = fdot2(BC2(t_), BC2(v_.x), acc0_);           \
            acc1_ = fdot2(BC2(wy[4 * c_ + 0]), BC2(v_.x), acc1_);                            \
            AREAD(t_, wxa[4 * c_ - 24]); acc0_ = fdot2(BC2(t_), BC2(v_.y), acc0_);           \
            acc1_ = fdot2(BC2(wy[4 * c_ + 1]), BC2(v_.y), acc1_);                            \
            AREAD(t_, wxa[4 * c_ - 23]); acc0_ = fdot2(BC2(t_), BC2(v_.z), acc0_);           \
            acc1_ = fdot2(BC2(wy[4 * c_ + 2]), BC2(v_.z), acc1_);                            \
            AREAD(t_, wxa[4 * c_ - 22]); acc0_ = fdot2(BC2(t_), BC2(v_.w), acc0_);           \
            acc1_ = fdot2(BC2(wy[4 * c_ + 3]), BC2(v_.w), acc1_);                            \
        }                                                                                    \
        {  /* c=12: h0 pairs 48,49 then h1 pairs 0,1 */                                      \
            float4 v_ = h4_[12];                                                             \
            AREAD(t_, wxa[23]); acc0_ = fdot2(BC2(t_), BC2(v_.x), acc0_);                    \
            acc1_ = fdot2(BC2(wy[48]), BC2(v_.x), acc1_);                                    \
            AREAD(t_, wxa[24]); acc0_ = fdot2(BC2(t_), BC2(v_.y), acc0_);                    \
            acc1_ = fdot2(BC2(wy[49]), BC2(v_.y), acc1_);                                    \
            AREAD(t_, wza[0]); acc1_ = fdot2(BC2(t_), BC2(v_.z), acc1_);                     \
            AREAD(t_, wza[1]); acc1_ = fdot2(BC2(t_), BC2(v_.w), acc1_);                     \
        }                                                                                    \
        _Pragma("unroll")                                                                    \
        for (int c_ = 13; c_ < 25; c_++) {  /* h1 pairs 2..49: wza AGPR */                   \
            float4 v_ = h4_[c_];                                                             \
            AREAD(t_, wza[4 * c_ - 50]); acc1_ = fdot2(BC2(t_), BC2(v_.x), acc1_);           \
            AREAD(t_, wza[4 * c_ - 49]); acc1_ = fdot2(BC2(t_), BC2(v_.y), acc1_);           \
            AREAD(t_, wza[4 * c_ - 48]); acc1_ = fdot2(BC2(t_), BC2(v_.z), acc1_);           \
            AREAD(t_, wza[4 * c_ - 47]); acc1_ = fdot2(BC2(t_), BC2(v_.w), acc1_);           \
        }                                                                                    \
        gates[j] = acc0_;                                                                    \
        gates[400 + j] = acc1_;                                                              \
    }                                                                                        \
    bar_lds();                                                                               \
    if (j < 100) {  /* layer-0 update, step T_ */                                            \
        float gi_ = gates[j], gf_ = gates[j + 100], gg_ = gates[j + 200], go_ = gates[j + 300]; \
        c0 = sigf(gf_) * c0 + sigf(gi_) * tanh_f(gg_);                                       \
        h0v = sigf(go_) * tanh_f(c0);                                                        \
        float hp_ = __shfl_xor(h0v, 1);                                                      \
        if (!(j & 1)) { h2 q_; q_.x = (_Float16)h0v; q_.y = (_Float16)hp_;                   \
                        hcat[j >> 1] = __builtin_bit_cast(unsigned int, q_); }               \
        if ((T_) == T_STEPS - 1) { outTail[j] = h0v; outTail[200 + j] = c0; }                \
    } else if (j >= 256 && j < 356) {  /* layer-1 update, step T_-1 */                       \
        if ((T_) >= 1) {                                                                     \
            int i_ = j - 256;                                                                \
            float gi_ = gates[400 + i_], gf_ = gates[500 + i_];                              \
            float gg_ = gates[600 + i_], go_ = gates[700 + i_];                              \
            c1 = sigf(gf_) * c1 + sigf(gi_) * tanh_f(gg_);                                   \
            h1v = sigf(go_) * tanh_f(c1);                                                    \
            h1s[(size_t)((T_) - 1) * 100 + i_] = h1v;                                        \
            float hp_ = __shfl_xor(h1v, 1);                                                  \
            if (!(i_ & 1)) { h2 q_; q_.x = (_Float16)h1v; q_.y = (_Float16)hp_;              \
                             hcat[50 + (i_ >> 1)] = __builtin_bit_cast(unsigned int, q_); }  \
        }                                                                                    \
    }                                                                                        \
    bar_lds();                                                                               \
} while (0)

__global__ __launch_bounds__(512) void k_scan(const _Float16* __restrict__ x0p,
                                              const float* __restrict__ Whh0,
                                              const float* __restrict__ Wih1,
                                              const float* __restrict__ Whh1,
                                              const float* __restrict__ bih1,
                                              const float* __restrict__ bhh1,
                                              float* __restrict__ h1s,
                                              float* __restrict__ outTail) {
    __shared__ __align__(16) unsigned int hcat[104];  // [0..49]=h0 pairs, [50..99]=h1 pairs
    __shared__ float gates[800];                      // [0..399]=gates0(t), [400..799]=gates1(t-1)
    const int j = threadIdx.x;

    float wx[25];   // arch: W_hh0 row j, pairs 0-24
    float wy[50];   // arch: W_ih1 row j
    float wxa[25];  // AGPR: W_hh0 row j, pairs 25-49
    float wza[50];  // AGPR: W_hh1 row j
    float b1c = 0.f, xa = 0.f, xb = 0.f;
    const _Float16* pxa = x0p + 800 + j;
    const _Float16* pxb = x0p + 1200 + j;

    if (j < 400) {
        const float2* p0 = (const float2*)(Whh0 + j * 100);
#pragma unroll
        for (int k = 0; k < 25; k++) wx[k] = packpair(p0[k]);
#pragma unroll
        for (int k = 0; k < 25; k++) { float pv = packpair(p0[25 + k]); AWRITE(wxa[k], pv); }
        const float2* p1 = (const float2*)(Wih1 + j * 100);
#pragma unroll
        for (int k = 0; k < 50; k++) wy[k] = packpair(p1[k]);
        const float2* p2 = (const float2*)(Whh1 + j * 100);
#pragma unroll
        for (int k = 0; k < 50; k++) { float pv = packpair(p2[k]); AWRITE(wza[k], pv); }
        b1c = bih1[j] + bhh1[j];
        xa = (float)x0p[j];        // x(0)
        xb = (float)x0p[400 + j];  // x(1)
    }
    if (j < 104) hcat[j] = 0u;
    float c0 = 0.f, c1 = 0.f, h0v = 0.f, h1v = 0.f;
    __syncthreads();

    for (int t = 0; t < T_STEPS; t += 2) {
        TICK(t, xa, pxa);      // distance-2 prefetch
        TICK(t + 1, xb, pxb);
    }

    // Drain tick (t == T_STEPS): gates1 for step T-1, then final layer-1 update.
    if (j < 400) {
        const float4* h4 = (const float4*)hcat;
        float acc1 = b1c, t_;
#pragma unroll
        for (int c = 0; c < 12; c++) {
            float4 v = h4[c];
            acc1 = fdot2(BC2(wy[4 * c + 0]), BC2(v.x), acc1);
            acc1 = fdot2(BC2(wy[4 * c + 1]), BC2(v.y), acc1);
            acc1 = fdot2(BC2(wy[4 * c + 2]), BC2(v.z), acc1);
            acc1 = fdot2(BC2(wy[4 * c + 3]), BC2(v.w), acc1);
        }
        {
            float4 v = h4[12];
            acc1 = fdot2(BC2(wy[48]), BC2(v.x), acc1);
            acc1 = fdot2(BC2(wy[49]), BC2(v.y), acc1);
            AREAD(t_, wza[0]); acc1 = fdot2(BC2(t_), BC2(v.z), acc1);
            AREAD(t_, wza[1]); acc1 = fdot2(BC2(t_), BC2(v.w), acc1);
        }
#pragma unroll
        for (int c = 13; c < 25; c++) {
            float4 v = h4[c];
            AREAD(t_, wza[4 * c - 50]); acc1 = fdot2(BC2(t_), BC2(v.x), acc1);
            AREAD(t_, wza[4 * c - 49]); acc1 = fdot2(BC2(t_), BC2(v.y), acc1);
            AREAD(t_, wza[4 * c - 48]); acc1 = fdot2(BC2(t_), BC2(v.z), acc1);
            AREAD(t_, wza[4 * c - 47]); acc1 = fdot2(BC2(t_), BC2(v.w), acc1);
        }
        gates[400 + j] = acc1;
    }
    bar_lds();
    if (j >= 256 && j < 356) {
        int i = j - 256;
        float gi = gates[400 + i], gf = gates[500 + i], gg = gates[600 + i], go = gates[700 + i];
        c1 = sigf(gf) * c1 + sigf(gi) * tanh_f(gg);
        h1v = sigf(go) * tanh_f(c1);
        h1s[(size_t)(T_STEPS - 1) * 100 + i] = h1v;
        outTail[100 + i] = h1v;
        outTail[300 + i] = c1;
    }
}

// ---------------- C: outputs[t][d] = h1s[t] . W_out[d] + b_out[d] ----------------
__global__ __launch_bounds__(320) void k_out(const float* __restrict__ h1s,
                                             const float* __restrict__ Wout,
                                             const float* __restrict__ bout,
                                             float* __restrict__ out) {
    __shared__ float hs[32 * 100];
    int t0 = blockIdx.x * 32;
    for (int idx = threadIdx.x; idx < 3200; idx += 320) hs[idx] = h1s[(size_t)t0 * 100 + idx];
    __syncthreads();
    int d = threadIdx.x;
    if (d < 300) {
        float acc[32];
#pragma unroll
        for (int i = 0; i < 32; i++) acc[i] = 0.f;
        const float4* w4 = (const float4*)(Wout + d * 100);
        const float4* h4 = (const float4*)hs;
        for (int j4 = 0; j4 < 25; j4++) {
            float4 w = w4[j4];
#pragma unroll
            for (int ti = 0; ti < 32; ti++) {
                float4 h = h4[ti * 25 + j4];
                acc[ti] += w.x * h.x + w.y * h.y + w.z * h.z + w.w * h.w;
            }
        }
        float bb = bout[d];
#pragma unroll
        for (int ti = 0; ti < 32; ti++) out[(size_t)(t0 + ti) * 300 + d] = acc[ti] + bb;
    }
}

extern "C" void kernel_launch(void* const* d_in, const int* in_sizes, int n_in,
                              void* d_out, int out_size, void* d_ws, size_t ws_size,
                              hipStream_t stream) {
    const float* inputs = (const float*)d_in[0];
    const float* W_inp  = (const float*)d_in[1];
    const float* b_inp  = (const float*)d_in[2];
    const float* W_ih0  = (const float*)d_in[3];
    const float* W_hh0  = (const float*)d_in[4];
    const float* b_ih0  = (const float*)d_in[5];
    const float* b_hh0  = (const float*)d_in[6];
    const float* W_ih1  = (const float*)d_in[7];
    const float* W_hh1  = (const float*)d_in[8];
    const float* b_ih1  = (const float*)d_in[9];
    const float* b_hh1  = (const float*)d_in[10];
    const float* W_out  = (const float*)d_in[11];
    const float* b_out  = (const float*)d_in[12];
    float* out = (float*)d_out;

    char* ws = (char*)d_ws;
    _Float16* x0p = (_Float16*)ws;                         // 32768*400*2 = 26,214,400 B
    float* h1s = (float*)(ws + 26214400);                  // 32768*100*4 = 13,107,200 B
    float* Wc  = (float*)(ws + 26214400 + 13107200);       // 400*300*4   =    480,000 B
    float* bc  = Wc + 120000;                              // 400*4 B

    k_precomp<<<471, 256, 0, stream>>>(W_inp, b_inp, W_ih0, b_ih0, b_hh0, Wc, bc);
    k_xproj<<<1024, 512, 0, stream>>>(inputs, Wc, bc, x0p);
    k_scan<<<1, 512, 0, stream>>>(x0p, W_hh0, W_ih1, W_hh1, b_ih1, b_hh1, h1s, out + OUT_BASE);
    k_out<<<1024, 320, 0, stream>>>(h1s, W_out, b_out, out);
}

// Round 6
// 45221.829 us; speedup vs baseline: 1.3367x; 1.3051x over previous
//
#include <hip/hip_runtime.h>

#define T_STEPS 32768
#define OUT_BASE 9830400  // 32768*300

typedef _Float16 h8 __attribute__((ext_vector_type(8)));
typedef _Float16 h2v __attribute__((ext_vector_type(2)));
typedef float f4 __attribute__((ext_vector_type(4)));

__device__ __forceinline__ float sigf(float x) { return 1.f / (1.f + __expf(-x)); }

__device__ __forceinline__ float tanh_f(float x) {
    float a = fabsf(x);
    float e = __expf(-2.f * a);
    float t = (1.f - e) / (1.f + e);
    return x < 0.f ? -t : t;
}

__device__ __forceinline__ unsigned int packh2(float a, float b) {
    h2v q; q[0] = (_Float16)a; q[1] = (_Float16)b;
    return __builtin_bit_cast(unsigned int, q);
}

// LDS-only barrier: no vmcnt(0) drain (x0p prefetch / h1s stores have no
// cross-thread dependency inside this kernel).
__device__ __forceinline__ void bar_lds() {
    asm volatile("s_waitcnt lgkmcnt(0)\n\ts_barrier" ::: "memory");
}

// ---------------- A0: Wc = W_ih_l0 @ W_inp  [400x300]; bc = W_ih_l0@b_inp + b_ih0 + b_hh0 ----------------
__global__ void k_precomp(const float* __restrict__ W_inp, const float* __restrict__ b_inp,
                          const float* __restrict__ W_ih0, const float* __restrict__ b_ih0,
                          const float* __restrict__ b_hh0,
                          float* __restrict__ Wc, float* __restrict__ bc) {
    int idx = blockIdx.x * 256 + threadIdx.x;
    if (idx < 120000) {
        int r = idx / 300, d = idx % 300;
        float acc = 0.f;
        for (int h = 0; h < 100; h++) acc += W_ih0[r * 100 + h] * W_inp[h * 300 + d];
        Wc[idx] = acc;
    } else if (idx < 120400) {
        int r = idx - 120000;
        float acc = b_ih0[r] + b_hh0[r];
        for (int h = 0; h < 100; h++) acc += W_ih0[r * 100 + h] * b_inp[h];
        bc[r] = acc;
    }
}

// ---------------- A1: x0p[t][r] = inputs[t] . Wc[r] + bc[r], stored f16 ----------------
__global__ __launch_bounds__(512) void k_xproj(const float* __restrict__ inp,
                                               const float* __restrict__ Wc,
                                               const float* __restrict__ bc,
                                               _Float16* __restrict__ x0p) {
    __shared__ float xs[32 * 300];
    int t0 = blockIdx.x * 32;
    for (int idx = threadIdx.x; idx < 9600; idx += 512) xs[idx] = inp[(size_t)t0 * 300 + idx];
    __syncthreads();
    int j = threadIdx.x;
    if (j < 400) {
        float acc[32];
#pragma unroll
        for (int i = 0; i < 32; i++) acc[i] = 0.f;
        const float4* w4 = (const float4*)(Wc + j * 300);
        const float4* x4 = (const float4*)xs;
        for (int d4 = 0; d4 < 75; d4++) {
            float4 w = w4[d4];
#pragma unroll
            for (int ti = 0; ti < 32; ti++) {
                float4 x = x4[ti * 75 + d4];
                acc[ti] += w.x * x.x + w.y * x.y + w.z * x.z + w.w * x.w;
            }
        }
        float bb = bc[j];
#pragma unroll
        for (int ti = 0; ti < 32; ti++)
            x0p[(size_t)(t0 + ti) * 400 + j] = (_Float16)(acc[ti] + bb);
    }
}

// ---------------- Scan: MFMA-based MV, pipelined layers (layer1 lags 1 tick) ----------------
// G[800] = W_big[800x224] . hc[224], hc = [h0(t-1) | h1(t-2) | zeros].
//   rows 0-399:   [W_hh0 | 0]          -> gates0(t) (x added in update phase)
//   rows 400-799: [W_ih1 | W_hh1 | 0]  -> gates1(t-1) (bias added in update phase)
// 16x16x32 f16 MFMA; A-fragments register-resident (AGPR-native, zero move cost).
// Per-wave tiles: L0 {wv, 8+wv, 16+wv} (+24 for wave0), L1 {25+wv, 33+wv, 41+wv} (+49 for wave7).
// B = broadcast hc: every lane ds_read_b128 at k=kt*32+quad*8 -> all 16 D-cols equal G.
// D extraction: lanes (lane&15)==0 write float4 (C/D: col=lane&15, row=quad*4+reg).
template <int NL0, int NL1>
__device__ __forceinline__ void scan_impl(
    const int j, unsigned int* hcat, float* gates,
    const _Float16* __restrict__ x0p,
    const float* __restrict__ Whh0, const float* __restrict__ Wih1,
    const float* __restrict__ Whh1,
    const float* __restrict__ bih1, const float* __restrict__ bhh1,
    float* __restrict__ h1s, float* __restrict__ outTail) {
    const int wv = j >> 6;
    const int lane = j & 63;
    const int quad = lane >> 4;
    const int m = lane & 15;

    int t0s[NL0], t1s[NL1];
    t0s[0] = wv; t0s[1] = 8 + wv; t0s[2] = 16 + wv;
    if (NL0 == 4) t0s[3] = 24;
    t1s[0] = 25 + wv; t1s[1] = 33 + wv; t1s[2] = 41 + wv;
    if (NL1 == 4) t1s[3] = 49;

    // ---- A-fragment init (one-time): A[m=lane&15][k=quad*8+e] ----
    h8 A0[NL0][4];
#pragma unroll
    for (int i = 0; i < NL0; i++) {
        int row = t0s[i] * 16 + m;
#pragma unroll
        for (int kt = 0; kt < 4; kt++) {
            h8 af;
#pragma unroll
            for (int e = 0; e < 8; e++) {
                int k = kt * 32 + quad * 8 + e;
                af[e] = (_Float16)(k < 100 ? Whh0[row * 100 + k] : 0.f);
            }
            A0[i][kt] = af;
        }
    }
    h8 A1[NL1][7];
#pragma unroll
    for (int i = 0; i < NL1; i++) {
        int row = t1s[i] * 16 + m - 400;
#pragma unroll
        for (int kt = 0; kt < 7; kt++) {
            h8 af;
#pragma unroll
            for (int e = 0; e < 8; e++) {
                int k = kt * 32 + quad * 8 + e;
                float v = 0.f;
                if (k < 100) v = Wih1[row * 100 + k];
                else if (k < 200) v = Whh1[row * 100 + k - 100];
                af[e] = (_Float16)v;
            }
            A1[i][kt] = af;
        }
    }

    // ---- update-lane state ----
    float c0 = 0.f, c1 = 0.f, h0v = 0.f, h1v = 0.f;
    float xc0 = 0, xc1 = 0, xc2 = 0, xc3 = 0, xn0 = 0, xn1 = 0, xn2 = 0, xn3 = 0;
    float b10 = 0, b11 = 0, b12 = 0, b13 = 0;
    if (j < 100) {
        const _Float16* p0 = x0p + j;
        xc0 = (float)p0[0]; xc1 = (float)p0[100]; xc2 = (float)p0[200]; xc3 = (float)p0[300];
        const _Float16* p1 = x0p + 400 + j;
        xn0 = (float)p1[0]; xn1 = (float)p1[100]; xn2 = (float)p1[200]; xn3 = (float)p1[300];
    }
    if (j >= 256 && j < 356) {
        int i = j - 256;
        b10 = bih1[i] + bhh1[i];
        b11 = bih1[i + 100] + bhh1[i + 100];
        b12 = bih1[i + 200] + bhh1[i + 200];
        b13 = bih1[i + 300] + bhh1[i + 300];
    }
    if (j < 112) hcat[j] = 0u;  // pairs 100-111 stay zero forever (k=200..223 pad)
    __syncthreads();

    const f4 fz = {0.f, 0.f, 0.f, 0.f};
    for (int t = 0; t < T_STEPS; t++) {
        // ---- MV phase ----
        f4 d0[NL0], d1[NL1];
#pragma unroll
        for (int i = 0; i < NL0; i++) d0[i] = fz;
#pragma unroll
        for (int i = 0; i < NL1; i++) d1[i] = fz;
#pragma unroll
        for (int kt = 0; kt < 7; kt++) {
            h8 b = *(const h8*)((const char*)hcat + kt * 64 + quad * 16);
            if (kt < 4) {
#pragma unroll
                for (int i = 0; i < NL0; i++)
                    d0[i] = __builtin_amdgcn_mfma_f32_16x16x32_f16(A0[i][kt], b, d0[i], 0, 0, 0);
            }
#pragma unroll
            for (int i = 0; i < NL1; i++)
                d1[i] = __builtin_amdgcn_mfma_f32_16x16x32_f16(A1[i][kt], b, d1[i], 0, 0, 0);
        }
        if (m == 0) {
#pragma unroll
            for (int i = 0; i < NL0; i++) *(f4*)(gates + t0s[i] * 16 + quad * 4) = d0[i];
#pragma unroll
            for (int i = 0; i < NL1; i++) *(f4*)(gates + t1s[i] * 16 + quad * 4) = d1[i];
        }
        bar_lds();
        // ---- update phase ----
        if (j < 100) {  // layer-0, step t
            float gi = gates[j] + xc0, gf = gates[j + 100] + xc1;
            float gg = gates[j + 200] + xc2, go = gates[j + 300] + xc3;
            c0 = sigf(gf) * c0 + sigf(gi) * tanh_f(gg);
            h0v = sigf(go) * tanh_f(c0);
            float hp = __shfl_xor(h0v, 1);
            if (!(j & 1)) hcat[j >> 1] = packh2(h0v, hp);
            if (t == T_STEPS - 1) { outTail[j] = h0v; outTail[200 + j] = c0; }
            xc0 = xn0; xc1 = xn1; xc2 = xn2; xc3 = xn3;  // rotate distance-2 prefetch
            int tn = (t + 2 < T_STEPS) ? t + 2 : T_STEPS - 1;
            const _Float16* p = x0p + (size_t)tn * 400 + j;
            xn0 = (float)p[0]; xn1 = (float)p[100]; xn2 = (float)p[200]; xn3 = (float)p[300];
        } else if (j >= 256 && j < 356) {  // layer-1, step t-1
            if (t >= 1) {
                int i = j - 256;
                float gi = gates[400 + i] + b10, gf = gates[500 + i] + b11;
                float gg = gates[600 + i] + b12, go = gates[700 + i] + b13;
                c1 = sigf(gf) * c1 + sigf(gi) * tanh_f(gg);
                h1v = sigf(go) * tanh_f(c1);
                h1s[(size_t)(t - 1) * 100 + i] = h1v;
                float hp = __shfl_xor(h1v, 1);
                if (!(i & 1)) hcat[50 + (i >> 1)] = packh2(h1v, hp);
            }
        }
        bar_lds();
    }

    // ---- drain: gates1(T-1) from h0(T-1), h1(T-2), then final layer-1 update ----
    {
        f4 d1[NL1];
#pragma unroll
        for (int i = 0; i < NL1; i++) d1[i] = fz;
#pragma unroll
        for (int kt = 0; kt < 7; kt++) {
            h8 b = *(const h8*)((const char*)hcat + kt * 64 + quad * 16);
#pragma unroll
            for (int i = 0; i < NL1; i++)
                d1[i] = __builtin_amdgcn_mfma_f32_16x16x32_f16(A1[i][kt], b, d1[i], 0, 0, 0);
        }
        if (m == 0) {
#pragma unroll
            for (int i = 0; i < NL1; i++) *(f4*)(gates + t1s[i] * 16 + quad * 4) = d1[i];
        }
        bar_lds();
        if (j >= 256 && j < 356) {
            int i = j - 256;
            float gi = gates[400 + i] + b10, gf = gates[500 + i] + b11;
            float gg = gates[600 + i] + b12, go = gates[700 + i] + b13;
            c1 = sigf(gf) * c1 + sigf(gi) * tanh_f(gg);
            h1v = sigf(go) * tanh_f(c1);
            h1s[(size_t)(T_STEPS - 1) * 100 + i] = h1v;
            outTail[100 + i] = h1v;
            outTail[300 + i] = c1;
        }
    }
}

__global__ __launch_bounds__(512) void k_scan(const _Float16* __restrict__ x0p,
                                              const float* __restrict__ Whh0,
                                              const float* __restrict__ Wih1,
                                              const float* __restrict__ Whh1,
                                              const float* __restrict__ bih1,
                                              const float* __restrict__ bhh1,
                                              float* __restrict__ h1s,
                                              float* __restrict__ outTail) {
    __shared__ __align__(16) unsigned int hcat[112];  // [0..49]=h0 pairs, [50..99]=h1 pairs, [100..111]=0
    __shared__ __align__(16) float gates[800];        // [0..399]=gates0(t), [400..799]=gates1(t-1)
    const int j = threadIdx.x;
    const int wv = j >> 6;
    // wave-uniform branches; all instantiations execute identical barrier sequences
    if (wv == 0)
        scan_impl<4, 3>(j, hcat, gates, x0p, Whh0, Wih1, Whh1, bih1, bhh1, h1s, outTail);
    else if (wv == 7)
        scan_impl<3, 4>(j, hcat, gates, x0p, Whh0, Wih1, Whh1, bih1, bhh1, h1s, outTail);
    else
        scan_impl<3, 3>(j, hcat, gates, x0p, Whh0, Wih1, Whh1, bih1, bhh1, h1s, outTail);
}

// ---------------- C: outputs[t][d] = h1s[t] . W_out[d] + b_out[d] ----------------
__global__ __launch_bounds__(320) void k_out(const float* __restrict__ h1s,
                                             const float* __restrict__ Wout,
                                             const float* __restrict__ bout,
                                             float* __restrict__ out) {
    __shared__ float hs[32 * 100];
    int t0 = blockIdx.x * 32;
    for (int idx = threadIdx.x; idx < 3200; idx += 320) hs[idx] = h1s[(size_t)t0 * 100 + idx];
    __syncthreads();
    int d = threadIdx.x;
    if (d < 300) {
        float acc[32];
#pragma unroll
        for (int i = 0; i < 32; i++) acc[i] = 0.f;
        const float4* w4 = (const float4*)(Wout + d * 100);
        const float4* h4 = (const float4*)hs;
        for (int j4 = 0; j4 < 25; j4++) {
            float4 w = w4[j4];
#pragma unroll
            for (int ti = 0; ti < 32; ti++) {
                float4 h = h4[ti * 25 + j4];
                acc[ti] += w.x * h.x + w.y * h.y + w.z * h.z + w.w * h.w;
            }
        }
        float bb = bout[d];
#pragma unroll
        for (int ti = 0; ti < 32; ti++) out[(size_t)(t0 + ti) * 300 + d] = acc[ti] + bb;
    }
}

extern "C" void kernel_launch(void* const* d_in, const int* in_sizes, int n_in,
                              void* d_out, int out_size, void* d_ws, size_t ws_size,
                              hipStream_t stream) {
    const float* inputs = (const float*)d_in[0];
    const float* W_inp  = (const float*)d_in[1];
    const float* b_inp  = (const float*)d_in[2];
    const float* W_ih0  = (const float*)d_in[3];
    const float* W_hh0  = (const float*)d_in[4];
    const float* b_ih0  = (const float*)d_in[5];
    const float* b_hh0  = (const float*)d_in[6];
    const float* W_ih1  = (const float*)d_in[7];
    const float* W_hh1  = (const float*)d_in[8];
    const float* b_ih1  = (const float*)d_in[9];
    const float* b_hh1  = (const float*)d_in[10];
    const float* W_out  = (const float*)d_in[11];
    const float* b_out  = (const float*)d_in[12];
    float* out = (float*)d_out;

    char* ws = (char*)d_ws;
    _Float16* x0p = (_Float16*)ws;                         // 32768*400*2 = 26,214,400 B
    float* h1s = (float*)(ws + 26214400);                  // 32768*100*4 = 13,107,200 B
    float* Wc  = (float*)(ws + 26214400 + 13107200);       // 400*300*4   =    480,000 B
    float* bc  = Wc + 120000;                              // 400*4 B

    k_precomp<<<471, 256, 0, stream>>>(W_inp, b_inp, W_ih0, b_ih0, b_hh0, Wc, bc);
    k_xproj<<<1024, 512, 0, stream>>>(inputs, Wc, bc, x0p);
    k_scan<<<1, 512, 0, stream>>>(x0p, W_hh0, W_ih1, W_hh1, b_ih1, b_hh1, h1s, out + OUT_BASE);
    k_out<<<1024, 320, 0, stream>>>(h1s, W_out, b_out, out);
}